// Round 11
// baseline (100.048 us; speedup 1.0000x reference)
//
#include <hip/hip_runtime.h>

// Chamfer loss: pred (2048,8,3) vs gt (2048,8,3) fp32. N=16384 pts/side.
// out = mean(min_m d) + mean(min_n d); 8-corner group-mean == global mean.
//
// R14: SINGLE-VARIABLE experiment on the 4-5x VALU bloat seen R8-R13.
// R13 books: source VALU ~5.2us/SIMD vs measured 27us busy -> ~4-5x
// instruction inflation, constant across structures. Prime suspect:
// VGPR_Count=32 every round -> allocator splits the unified file and
// runs MFMA C/D through AGPRs: ~4 v_accvgpr_write (zero C) + ~4
// v_accvgpr_read (move D for v_max3) per MFMA = +8 VALU/MFMA = the 4-5x.
// At 64-VGPR the wave cap (8/SIMD) is already reached - squeezing to 32
// buys NOTHING; it's the default occupancy heuristic misfiring.
// Change vs R13 (byte-identical otherwise):
//  - chamfer_rowmin: __launch_bounds__(256, 1) -> min 1 wave/EU -> reg
//    budget 512 -> no incentive to shunt C/D into AGPRs.
// Predicted: VGPR >=80, dur 42.5 -> 8-15us, VALU busy 27 -> ~6us.
// Falsification: VGPR stays <=48 or VALU busy >20us -> R15 = inline-asm
// inner loop with explicit accvgpr control.
// Verified invariants: bf16 3-way-split K-packing (absmax 0.0 since R5),
// kg-major fragment layout (1KB-contiguous wave loads), no LDS staging
// (B is L2-resident), one DPP flush per wave, no hot-loop atomics.
// Fixed per round: 268MB ws re-poison fill ~40us + ~8us launch gaps.

#define NPTS   16384
#define BLOCK  256            // 4 waves
#define XW     64             // x-points per wave (4 tiles, af in 16 VGPR)
#define XCH    256            // x-points per block
#define NXB    (NPTS / XCH)   // 64
#define YRNG   1024           // y-points per block (64 tiles)
#define NYR    (NPTS / YRNG)  // 16
#define NTIL   (YRNG / 16)    // 64 y-tiles per range
#define ONEBF  0x3F80         // bf16 1.0

// ws: [0,4MB) packed Ppa|Ppb|Pga|Pgb (1MB each) | [4MB,6MB) part[32][NPTS]
//   slices 0..15  = pred row-min partials, id = yr
//   slices 16..31 = gt   row-min partials, id = 16+yr
#define WS_PPB  (1u << 20)
#define WS_PGA  (2u << 20)
#define WS_PGB  (3u << 20)
#define WS_PART (4u << 20)

typedef __attribute__((ext_vector_type(8))) short bf16x8;
typedef __attribute__((ext_vector_type(4))) float f32x4;

__device__ inline unsigned short f2bf(float f) {  // fp32 -> bf16 RNE
    unsigned int u = __float_as_uint(f);
    return (unsigned short)((u + 0x7FFFu + ((u >> 16) & 1u)) >> 16);
}
__device__ inline float bf2f(unsigned short h) {
    return __uint_as_float((unsigned int)h << 16);
}
__device__ inline void split3(float v, unsigned short* s) {
    unsigned short h = f2bf(v);  float r = v - bf2f(h);
    unsigned short m = f2bf(r);  r -= bf2f(m);
    s[0] = h; s[1] = m; s[2] = f2bf(r);
}

// K-slot map (identical order on A and B rows => lane->K bijection cancels):
//   s=c*3+d, c<6: cross combos (i,j)=(h,h)(h,m)(m,h)(h,l)(m,m)(l,h)
//   s=18..20: a=split3(-|p|^2/2), b=1 ; s=21..23: a=1, b=split3(-|p|^2/2)
//   s=24..31: 0   => S[r][c] = x.y - |x|^2/2 - |y|^2/2 = -d2/2
__device__ inline void build_rows(const float p[3], unsigned short* a,
                                  unsigned short* b) {
    const int CI[6] = {0, 0, 1, 0, 1, 2};
    const int CJ[6] = {0, 1, 0, 2, 1, 0};
    unsigned short xs[3][3], nn[3], t[3];
#pragma unroll
    for (int d = 0; d < 3; ++d) {
        split3(p[d], t);
        xs[0][d] = t[0]; xs[1][d] = t[1]; xs[2][d] = t[2];
    }
    split3(-0.5f * (p[0]*p[0] + p[1]*p[1] + p[2]*p[2]), nn);
#pragma unroll
    for (int c = 0; c < 6; ++c)
#pragma unroll
        for (int d = 0; d < 3; ++d) {
            a[c*3+d] = xs[CI[c]][d];
            b[c*3+d] = xs[CJ[c]][d];
        }
#pragma unroll
    for (int k = 0; k < 3; ++k) {
        a[18+k] = nn[k];  b[18+k] = ONEBF;
        a[21+k] = ONEBF;  b[21+k] = nn[k];
    }
#pragma unroll
    for (int k = 24; k < 32; ++k) { a[k] = 0; b[k] = 0; }
}

// Fragment-swizzled store (R12-verified): point i, K-chunk kg -> uint4 slot
// (i/16)*64 + kg*16 + (i%16); lane (col,kg) reads frag at slot
// tile*64 + kg*16 + col -> wave reads a contiguous 1KB line per instr.
__device__ inline void store_row_swz(uint4* dst4, int i, const unsigned short* s) {
    unsigned int w[16];
#pragma unroll
    for (int k = 0; k < 16; ++k)
        w[k] = (unsigned int)s[2*k] | ((unsigned int)s[2*k+1] << 16);
    const int base = (i >> 4) * 64 + (i & 15);
#pragma unroll
    for (int kgc = 0; kgc < 4; ++kgc)
        dst4[base + kgc * 16] = make_uint4(w[4*kgc], w[4*kgc+1],
                                           w[4*kgc+2], w[4*kgc+3]);
}

__global__ __launch_bounds__(256) void pack_points(
        const float* __restrict__ pred, const float* __restrict__ gt,
        unsigned short* __restrict__ Ppa, unsigned short* __restrict__ Ppb,
        unsigned short* __restrict__ Pga, unsigned short* __restrict__ Pgb,
        float* __restrict__ out) {
    const int i = blockIdx.x * 256 + threadIdx.x;
    if (i == 0) out[0] = 0.0f;  // replaces a memset dispatch
    if (i >= NPTS) return;
    float p[3] = {pred[3*i], pred[3*i+1], pred[3*i+2]};
    float q[3] = {gt[3*i],   gt[3*i+1],   gt[3*i+2]};
    unsigned short ra[32], rb[32];
    build_rows(p, ra, rb);
    store_row_swz(reinterpret_cast<uint4*>(Ppa), i, ra);
    store_row_swz(reinterpret_cast<uint4*>(Ppb), i, rb);
    build_rows(q, ra, rb);
    store_row_swz(reinterpret_cast<uint4*>(Pga), i, ra);
    store_row_swz(reinterpret_cast<uint4*>(Pgb), i, rb);
}

// DPP rotate-max within 16-lane rows (VALU pipe; verified R6-R13).
template <int CTRL>
__device__ inline float rormax(float v) {
    int t = __builtin_amdgcn_update_dpp(0, __float_as_int(v), CTRL, 0xF, 0xF,
                                        false);
    return fmaxf(v, __int_as_float(t));
}

__global__ __launch_bounds__(BLOCK, 1) void chamfer_rowmin(
        const unsigned short* __restrict__ Ppa,
        const unsigned short* __restrict__ Ppb,
        const unsigned short* __restrict__ Pga,
        const unsigned short* __restrict__ Pgb,
        float* __restrict__ part) {
    const int xb  = blockIdx.x;          // fastest: blocks sharing yr adjacent
    const int yr  = blockIdx.y;
    const int dir = blockIdx.z;
    const unsigned short* __restrict__ Ap = dir ? Pga : Ppa;  // rows = X side
    const unsigned short* __restrict__ Bp = dir ? Ppb : Pgb;  // cols = Y side
    const int tid = threadIdx.x;
    const int lane = tid & 63, w = tid >> 6;
    const int col = lane & 15, kg = lane >> 4;
    const int frag = kg * 16 + col;      // uint4 index of this lane's frag

    __shared__ float rowacc[XCH];        // 1 KB epilogue buffer

    // A-frags: wave's 4 x-tiles (each load = contiguous 1KB line)
    const uint4* ap = reinterpret_cast<const uint4*>(Ap);
    const int tile0 = xb * 16 + w * 4;
    bf16x8 af[4];
#pragma unroll
    for (int xi = 0; xi < 4; ++xi)
        af[xi] = *reinterpret_cast<const bf16x8*>(&ap[(tile0 + xi) * 64 + frag]);

    f32x4 rmax[4];
#pragma unroll
    for (int xi = 0; xi < 4; ++xi)
        rmax[xi] = (f32x4){-3.0e38f, -3.0e38f, -3.0e38f, -3.0e38f};

    const f32x4 z4 = {0.0f, 0.0f, 0.0f, 0.0f};

    // hot loop: 2 global loads (L2-hit) + 8 MFMA + 16 v_max3 per step.
    // No LDS, no barriers, no flushes.
    const uint4* bp = reinterpret_cast<const uint4*>(Bp)
                      + (size_t)(yr * NTIL) * 64 + frag;
#pragma unroll 4
    for (int t = 0; t < NTIL; t += 2) {
        bf16x8 b0 = *reinterpret_cast<const bf16x8*>(&bp[(t + 0) * 64]);
        bf16x8 b1 = *reinterpret_cast<const bf16x8*>(&bp[(t + 1) * 64]);
#pragma unroll
        for (int xi = 0; xi < 4; ++xi) {
            f32x4 A = __builtin_amdgcn_mfma_f32_16x16x32_bf16(af[xi], b0, z4, 0, 0, 0);
            f32x4 B = __builtin_amdgcn_mfma_f32_16x16x32_bf16(af[xi], b1, z4, 0, 0, 0);
            rmax[xi].x = fmaxf(fmaxf(A.x, B.x), rmax[xi].x);  // v_max3
            rmax[xi].y = fmaxf(fmaxf(A.y, B.y), rmax[xi].y);
            rmax[xi].z = fmaxf(fmaxf(A.z, B.z), rmax[xi].z);
            rmax[xi].w = fmaxf(fmaxf(A.w, B.w), rmax[xi].w);
        }
    }

    // flush ONCE per wave: DPP ror-max over 16 cols, park in LDS,
    // one coalesced 1KB store per block.
#pragma unroll
    for (int xi = 0; xi < 4; ++xi) {
#pragma unroll
        for (int c = 0; c < 4; ++c) {
            float v = rmax[xi][c];
            v = rormax<0x121>(v);
            v = rormax<0x122>(v);
            v = rormax<0x124>(v);
            v = rormax<0x128>(v);
            if (col == 0)
                rowacc[w * XW + xi * 16 + kg * 4 + c] = fmaxf(-2.0f * v, 0.0f);
        }
    }
    __syncthreads();
    part[(size_t)(dir * NYR + yr) * NPTS + xb * XCH + tid] = rowacc[tid];
}

__global__ __launch_bounds__(256) void chamfer_reduce(
        const float* __restrict__ part, float* __restrict__ out) {
    const int gid = blockIdx.x * 256 + threadIdx.x;  // 32 blocks x 256
    const int side = gid >> 12;                      // 4096 f32x4 per side
    const int idx4 = (gid & 4095) * 4;
    const float* base = part + (size_t)side * NYR * NPTS + idx4;
    float4 m = make_float4(3.0e38f, 3.0e38f, 3.0e38f, 3.0e38f);
#pragma unroll
    for (int c = 0; c < NYR; ++c) {
        float4 v = *reinterpret_cast<const float4*>(base + (size_t)c * NPTS);
        m.x = fminf(m.x, v.x); m.y = fminf(m.y, v.y);
        m.z = fminf(m.z, v.z); m.w = fminf(m.w, v.w);
    }
    float s = sqrtf(m.x) + sqrtf(m.y) + sqrtf(m.z) + sqrtf(m.w);
#pragma unroll
    for (int o = 32; o > 0; o >>= 1)
        s += __shfl_down(s, o, 64);
    if ((threadIdx.x & 63) == 0)
        atomicAdd(out, s * (1.0f / (float)NPTS));
}

extern "C" void kernel_launch(void* const* d_in, const int* in_sizes, int n_in,
                              void* d_out, int out_size, void* d_ws, size_t ws_size,
                              hipStream_t stream) {
    const float* pred = (const float*)d_in[0];
    const float* gt   = (const float*)d_in[1];
    float* out        = (float*)d_out;
    unsigned short* Ppa = (unsigned short*)d_ws;
    unsigned short* Ppb = (unsigned short*)((char*)d_ws + WS_PPB);
    unsigned short* Pga = (unsigned short*)((char*)d_ws + WS_PGA);
    unsigned short* Pgb = (unsigned short*)((char*)d_ws + WS_PGB);
    float* part         = (float*)((char*)d_ws + WS_PART);

    hipLaunchKernelGGL(pack_points, dim3(NPTS / 256), dim3(256), 0, stream,
                       pred, gt, Ppa, Ppb, Pga, Pgb, out);
    hipLaunchKernelGGL(chamfer_rowmin, dim3(NXB, NYR, 2), dim3(BLOCK), 0, stream,
                       Ppa, Ppb, Pga, Pgb, part);
    hipLaunchKernelGGL(chamfer_reduce, dim3(2 * NPTS / 1024), dim3(256), 0, stream,
                       part, out);
}

// Round 12
// 94.423 us; speedup vs baseline: 1.0596x; 1.0596x over previous
//
#include <hip/hip_runtime.h>

// Chamfer loss: pred (2048,8,3) vs gt (2048,8,3) fp32. N=16384 pts/side.
// out = mean(min_m d) + mean(min_n d); 8-corner group-mean == global mean.
//
// R15: discriminate the last two theories for the stubborn ~45us kernel.
// R13/R14 books: both pipe counters imply effective clock ~0.7-0.9 GHz
// (3x below nominal) OR hidden instruction inflation. Candidates:
//  (a) DPM clock throttle after the 80%-HBM re-poison fill (~40us) that
//      precedes us every timed iteration (ramp latency ~tens of us);
//  (b) MFMA C/D parked in AGPRs (VGPR_Count=32 vs ~60 live) -> hidden
//      v_accvgpr_read/write per MFMA inflating VALU busy.
// This round kills (b) structurally:
//  - inner MFMA pair emitted as INLINE ASM with "=&v" outputs / "v"
//    inputs: register class forced to arch VGPRs, accvgpr moves
//    impossible. s_nop padding covers MFMA->VALU RAW hazard (hazard
//    recognizer may not model inline-asm MFMA); leading s_nop 1 covers
//    VALU-write->MFMA-read on the b-copies.
//  - one-step-ahead B prefetch: loads for step t+2 issued before the
//    compute of step t -> L2 latency (~200cyc) off the critical path.
// Everything else byte-identical to R13 (verified, absmax 0.0 since R5):
// bf16 3-way-split K-packing, kg-major fragment layout (1KB-contiguous
// wave loads), unidirectional two-pass, no LDS staging, one DPP flush
// per wave, coalesced partial stores, no hot-loop atomics.
// Prediction: accvgpr theory -> VGPR>=64, kernel 45->18-28us. Unchanged
// -> clock-throttle confirmed -> at harness floor.

#define NPTS   16384
#define BLOCK  256            // 4 waves
#define XW     64             // x-points per wave (4 tiles, af in 16 VGPR)
#define XCH    256            // x-points per block
#define NXB    (NPTS / XCH)   // 64
#define YRNG   1024           // y-points per block (64 tiles)
#define NYR    (NPTS / YRNG)  // 16
#define NTIL   (YRNG / 16)    // 64 y-tiles per range
#define ONEBF  0x3F80         // bf16 1.0

// ws: [0,4MB) packed Ppa|Ppb|Pga|Pgb (1MB each) | [4MB,6MB) part[32][NPTS]
#define WS_PPB  (1u << 20)
#define WS_PGA  (2u << 20)
#define WS_PGB  (3u << 20)
#define WS_PART (4u << 20)

typedef __attribute__((ext_vector_type(8))) short bf16x8;
typedef __attribute__((ext_vector_type(4))) float f32x4;
typedef __attribute__((ext_vector_type(4))) unsigned int u32x4;

__device__ inline unsigned short f2bf(float f) {  // fp32 -> bf16 RNE
    unsigned int u = __float_as_uint(f);
    return (unsigned short)((u + 0x7FFFu + ((u >> 16) & 1u)) >> 16);
}
__device__ inline float bf2f(unsigned short h) {
    return __uint_as_float((unsigned int)h << 16);
}
__device__ inline void split3(float v, unsigned short* s) {
    unsigned short h = f2bf(v);  float r = v - bf2f(h);
    unsigned short m = f2bf(r);  r -= bf2f(m);
    s[0] = h; s[1] = m; s[2] = f2bf(r);
}

// K-slot map (identical order on A and B rows => lane->K bijection cancels):
//   s=c*3+d, c<6: cross combos (i,j)=(h,h)(h,m)(m,h)(h,l)(m,m)(l,h)
//   s=18..20: a=split3(-|p|^2/2), b=1 ; s=21..23: a=1, b=split3(-|p|^2/2)
//   s=24..31: 0   => S[r][c] = x.y - |x|^2/2 - |y|^2/2 = -d2/2
__device__ inline void build_rows(const float p[3], unsigned short* a,
                                  unsigned short* b) {
    const int CI[6] = {0, 0, 1, 0, 1, 2};
    const int CJ[6] = {0, 1, 0, 2, 1, 0};
    unsigned short xs[3][3], nn[3], t[3];
#pragma unroll
    for (int d = 0; d < 3; ++d) {
        split3(p[d], t);
        xs[0][d] = t[0]; xs[1][d] = t[1]; xs[2][d] = t[2];
    }
    split3(-0.5f * (p[0]*p[0] + p[1]*p[1] + p[2]*p[2]), nn);
#pragma unroll
    for (int c = 0; c < 6; ++c)
#pragma unroll
        for (int d = 0; d < 3; ++d) {
            a[c*3+d] = xs[CI[c]][d];
            b[c*3+d] = xs[CJ[c]][d];
        }
#pragma unroll
    for (int k = 0; k < 3; ++k) {
        a[18+k] = nn[k];  b[18+k] = ONEBF;
        a[21+k] = ONEBF;  b[21+k] = nn[k];
    }
#pragma unroll
    for (int k = 24; k < 32; ++k) { a[k] = 0; b[k] = 0; }
}

// Fragment-swizzled store (R12-verified): point i, K-chunk kg -> uint4 slot
// (i/16)*64 + kg*16 + (i%16); lane (col,kg) reads frag at slot
// tile*64 + kg*16 + col -> wave reads a contiguous 1KB line per instr.
__device__ inline void store_row_swz(uint4* dst4, int i, const unsigned short* s) {
    unsigned int w[16];
#pragma unroll
    for (int k = 0; k < 16; ++k)
        w[k] = (unsigned int)s[2*k] | ((unsigned int)s[2*k+1] << 16);
    const int base = (i >> 4) * 64 + (i & 15);
#pragma unroll
    for (int kgc = 0; kgc < 4; ++kgc)
        dst4[base + kgc * 16] = make_uint4(w[4*kgc], w[4*kgc+1],
                                           w[4*kgc+2], w[4*kgc+3]);
}

__global__ __launch_bounds__(256) void pack_points(
        const float* __restrict__ pred, const float* __restrict__ gt,
        unsigned short* __restrict__ Ppa, unsigned short* __restrict__ Ppb,
        unsigned short* __restrict__ Pga, unsigned short* __restrict__ Pgb,
        float* __restrict__ out) {
    const int i = blockIdx.x * 256 + threadIdx.x;
    if (i == 0) out[0] = 0.0f;  // replaces a memset dispatch
    if (i >= NPTS) return;
    float p[3] = {pred[3*i], pred[3*i+1], pred[3*i+2]};
    float q[3] = {gt[3*i],   gt[3*i+1],   gt[3*i+2]};
    unsigned short ra[32], rb[32];
    build_rows(p, ra, rb);
    store_row_swz(reinterpret_cast<uint4*>(Ppa), i, ra);
    store_row_swz(reinterpret_cast<uint4*>(Ppb), i, rb);
    build_rows(q, ra, rb);
    store_row_swz(reinterpret_cast<uint4*>(Pga), i, ra);
    store_row_swz(reinterpret_cast<uint4*>(Pgb), i, rb);
}

// DPP rotate-max within 16-lane rows (VALU pipe; verified R6-R14).
template <int CTRL>
__device__ inline float rormax(float v) {
    int t = __builtin_amdgcn_update_dpp(0, __float_as_int(v), CTRL, 0xF, 0xF,
                                        false);
    return fmaxf(v, __int_as_float(t));
}

__global__ __launch_bounds__(BLOCK, 1) void chamfer_rowmin(
        const unsigned short* __restrict__ Ppa,
        const unsigned short* __restrict__ Ppb,
        const unsigned short* __restrict__ Pga,
        const unsigned short* __restrict__ Pgb,
        float* __restrict__ part) {
    const int xb  = blockIdx.x;
    const int yr  = blockIdx.y;
    const int dir = blockIdx.z;
    const unsigned short* __restrict__ Ap = dir ? Pga : Ppa;  // rows = X side
    const unsigned short* __restrict__ Bp = dir ? Ppb : Pgb;  // cols = Y side
    const int tid = threadIdx.x;
    const int lane = tid & 63, w = tid >> 6;
    const int col = lane & 15, kg = lane >> 4;
    const int frag = kg * 16 + col;      // uint4 index of this lane's frag

    __shared__ float rowacc[XCH];        // 1 KB epilogue buffer

    // A-frags: wave's 4 x-tiles (each load = contiguous 1KB line)
    const uint4* ap = reinterpret_cast<const uint4*>(Ap);
    const int tile0 = xb * 16 + w * 4;
    u32x4 af[4];
#pragma unroll
    for (int xi = 0; xi < 4; ++xi)
        af[xi] = *reinterpret_cast<const u32x4*>(&ap[(tile0 + xi) * 64 + frag]);

    f32x4 rmax[4];
#pragma unroll
    for (int xi = 0; xi < 4; ++xi)
        rmax[xi] = (f32x4){-3.0e38f, -3.0e38f, -3.0e38f, -3.0e38f};

    const u32x4 zz = {0u, 0u, 0u, 0u};

    // hot loop: step t computes tiles t,t+1 while the loads for t+2,t+3
    // are already in flight (1-step-ahead prefetch).
    const uint4* bp = reinterpret_cast<const uint4*>(Bp)
                      + (size_t)(yr * NTIL) * 64 + frag;
    u32x4 b0 = *reinterpret_cast<const u32x4*>(&bp[0]);
    u32x4 b1 = *reinterpret_cast<const u32x4*>(&bp[64]);
#pragma unroll 1
    for (int t = 0; t < NTIL; t += 2) {
        u32x4 c0 = b0, c1 = b1;
        if (t + 2 < NTIL) {
            b0 = *reinterpret_cast<const u32x4*>(&bp[(t + 2) * 64]);
            b1 = *reinterpret_cast<const u32x4*>(&bp[(t + 3) * 64]);
        }
#pragma unroll
        for (int xi = 0; xi < 4; ++xi) {
            f32x4 A, B;
            // Inline asm: D forced into arch VGPRs ("=&v") -> no accvgpr
            // shuttling possible. s_nop 1 covers VALU-write->MFMA-read on
            // c0/c1; trailing s_nops cover MFMA-write->VALU-read on A/B.
            asm("s_nop 1\n\t"
                "v_mfma_f32_16x16x32_bf16 %0, %2, %3, %5\n\t"
                "v_mfma_f32_16x16x32_bf16 %1, %2, %4, %5\n\t"
                "s_nop 7\n\t"
                "s_nop 7\n\t"
                "s_nop 3"
                : "=&v"(A), "=&v"(B)
                : "v"(af[xi]), "v"(c0), "v"(c1), "v"(zz));
            rmax[xi].x = fmaxf(fmaxf(A.x, B.x), rmax[xi].x);  // v_max3
            rmax[xi].y = fmaxf(fmaxf(A.y, B.y), rmax[xi].y);
            rmax[xi].z = fmaxf(fmaxf(A.z, B.z), rmax[xi].z);
            rmax[xi].w = fmaxf(fmaxf(A.w, B.w), rmax[xi].w);
        }
    }

    // flush ONCE per wave: DPP ror-max over 16 cols, park in LDS,
    // one coalesced 1KB store per block.
#pragma unroll
    for (int xi = 0; xi < 4; ++xi) {
#pragma unroll
        for (int c = 0; c < 4; ++c) {
            float v = rmax[xi][c];
            v = rormax<0x121>(v);
            v = rormax<0x122>(v);
            v = rormax<0x124>(v);
            v = rormax<0x128>(v);
            if (col == 0)
                rowacc[w * XW + xi * 16 + kg * 4 + c] = fmaxf(-2.0f * v, 0.0f);
        }
    }
    __syncthreads();
    part[(size_t)(dir * NYR + yr) * NPTS + xb * XCH + tid] = rowacc[tid];
}

__global__ __launch_bounds__(256) void chamfer_reduce(
        const float* __restrict__ part, float* __restrict__ out) {
    const int gid = blockIdx.x * 256 + threadIdx.x;  // 32 blocks x 256
    const int side = gid >> 12;                      // 4096 f32x4 per side
    const int idx4 = (gid & 4095) * 4;
    const float* base = part + (size_t)side * NYR * NPTS + idx4;
    float4 m = make_float4(3.0e38f, 3.0e38f, 3.0e38f, 3.0e38f);
#pragma unroll
    for (int c = 0; c < NYR; ++c) {
        float4 v = *reinterpret_cast<const float4*>(base + (size_t)c * NPTS);
        m.x = fminf(m.x, v.x); m.y = fminf(m.y, v.y);
        m.z = fminf(m.z, v.z); m.w = fminf(m.w, v.w);
    }
    float s = sqrtf(m.x) + sqrtf(m.y) + sqrtf(m.z) + sqrtf(m.w);
#pragma unroll
    for (int o = 32; o > 0; o >>= 1)
        s += __shfl_down(s, o, 64);
    if ((threadIdx.x & 63) == 0)
        atomicAdd(out, s * (1.0f / (float)NPTS));
}

extern "C" void kernel_launch(void* const* d_in, const int* in_sizes, int n_in,
                              void* d_out, int out_size, void* d_ws, size_t ws_size,
                              hipStream_t stream) {
    const float* pred = (const float*)d_in[0];
    const float* gt   = (const float*)d_in[1];
    float* out        = (float*)d_out;
    unsigned short* Ppa = (unsigned short*)d_ws;
    unsigned short* Ppb = (unsigned short*)((char*)d_ws + WS_PPB);
    unsigned short* Pga = (unsigned short*)((char*)d_ws + WS_PGA);
    unsigned short* Pgb = (unsigned short*)((char*)d_ws + WS_PGB);
    float* part         = (float*)((char*)d_ws + WS_PART);

    hipLaunchKernelGGL(pack_points, dim3(NPTS / 256), dim3(256), 0, stream,
                       pred, gt, Ppa, Ppb, Pga, Pgb, out);
    hipLaunchKernelGGL(chamfer_rowmin, dim3(NXB, NYR, 2), dim3(BLOCK), 0, stream,
                       Ppa, Ppb, Pga, Pgb, part);
    hipLaunchKernelGGL(chamfer_reduce, dim3(2 * NPTS / 1024), dim3(256), 0, stream,
                       part, out);
}

// Round 13
// 90.304 us; speedup vs baseline: 1.1079x; 1.0456x over previous
//
#include <hip/hip_runtime.h>

// Chamfer loss: pred (2048,8,3) vs gt (2048,8,3) fp32. N=16384 pts/side.
// out = mean(min_m d) + mean(min_n d); 8-corner group-mean == global mean.
//
// R16: L2-BANDWIDTH theory. R15 established VGPR_Count=32 is bogus
// reporting (50+ live, zero scratch traffic) -> spill/AGPR theories were
// phantoms. Real ledger: 8192 waves x 64KB B-range = 512MB through L2
// per pass; at realized ~12TB/s that IS the ~40us kernel. Fixes:
//  - XW 64->128 (af[8]+rmax[8]): halves wave count -> 256MB logical.
//  - B staged in LDS, SHARED by the block's 4 waves (8KB chunks, double
//    buffer, ONE barrier/chunk, global loads issued post-barrier so L2
//    latency hides under the chunk's 64 MFMAs): L2 traffic = 1024
//    blocks x 64KB = 64MB; re-reads ride the LDS pipe (~9K cyc/CU).
//  - model: MFMA 9.9K || VALU 10.5K || LDS 9.4K/CU || L2 4.6K cyc/SIMD
//    ~= 4.6us ideal, 12-18us with session-typical slack.
// Kept verified: bf16 3-way-split K-packing (absmax 0.0 since R5),
// kg-major fragment layout, inline-asm MFMA pairs w/ R15 hazard padding,
// one DPP flush/wave, coalesced partial stores, no hot-loop atomics.
// Watch: WRITE_SIZE blowup = real spill (af+rmax ~98 live); rowmin
// >=30us with clean counters = L2 theory dead -> clock throttle floor.

#define NPTS   16384
#define BLOCK  256            // 4 waves
#define XW     128            // x-points per wave (8 tiles, af in 32 VGPR)
#define XCH    512            // x-points per block (32 tiles)
#define NXB    (NPTS / XCH)   // 32
#define YRNG   1024           // y-points per block (64 tiles)
#define NYR    (NPTS / YRNG)  // 16
#define CHT    8              // y-tiles per LDS chunk (8 KB)
#define NCH    (YRNG / (CHT * 16))  // 8 chunks
#define ONEBF  0x3F80         // bf16 1.0

// ws: [0,4MB) packed Ppa|Ppb|Pga|Pgb (1MB each) | [4MB,6MB) part[32][NPTS]
//   slices 0..15 = pred row-min partials (yr), 16..31 = gt (16+yr)
#define WS_PPB  (1u << 20)
#define WS_PGA  (2u << 20)
#define WS_PGB  (3u << 20)
#define WS_PART (4u << 20)

typedef __attribute__((ext_vector_type(8))) short bf16x8;
typedef __attribute__((ext_vector_type(4))) float f32x4;
typedef __attribute__((ext_vector_type(4))) unsigned int u32x4;

__device__ inline unsigned short f2bf(float f) {  // fp32 -> bf16 RNE
    unsigned int u = __float_as_uint(f);
    return (unsigned short)((u + 0x7FFFu + ((u >> 16) & 1u)) >> 16);
}
__device__ inline float bf2f(unsigned short h) {
    return __uint_as_float((unsigned int)h << 16);
}
__device__ inline void split3(float v, unsigned short* s) {
    unsigned short h = f2bf(v);  float r = v - bf2f(h);
    unsigned short m = f2bf(r);  r -= bf2f(m);
    s[0] = h; s[1] = m; s[2] = f2bf(r);
}

// K-slot map (identical order on A and B rows => lane->K bijection cancels):
//   s=c*3+d, c<6: cross combos (i,j)=(h,h)(h,m)(m,h)(h,l)(m,m)(l,h)
//   s=18..20: a=split3(-|p|^2/2), b=1 ; s=21..23: a=1, b=split3(-|p|^2/2)
//   s=24..31: 0   => S[r][c] = x.y - |x|^2/2 - |y|^2/2 = -d2/2
__device__ inline void build_rows(const float p[3], unsigned short* a,
                                  unsigned short* b) {
    const int CI[6] = {0, 0, 1, 0, 1, 2};
    const int CJ[6] = {0, 1, 0, 2, 1, 0};
    unsigned short xs[3][3], nn[3], t[3];
#pragma unroll
    for (int d = 0; d < 3; ++d) {
        split3(p[d], t);
        xs[0][d] = t[0]; xs[1][d] = t[1]; xs[2][d] = t[2];
    }
    split3(-0.5f * (p[0]*p[0] + p[1]*p[1] + p[2]*p[2]), nn);
#pragma unroll
    for (int c = 0; c < 6; ++c)
#pragma unroll
        for (int d = 0; d < 3; ++d) {
            a[c*3+d] = xs[CI[c]][d];
            b[c*3+d] = xs[CJ[c]][d];
        }
#pragma unroll
    for (int k = 0; k < 3; ++k) {
        a[18+k] = nn[k];  b[18+k] = ONEBF;
        a[21+k] = ONEBF;  b[21+k] = nn[k];
    }
#pragma unroll
    for (int k = 24; k < 32; ++k) { a[k] = 0; b[k] = 0; }
}

// Fragment-swizzled store (R12-verified): point i, K-chunk kg -> uint4 slot
// (i/16)*64 + kg*16 + (i%16); lane (col,kg) reads frag at slot
// tile*64 + kg*16 + col -> wave reads a contiguous 1KB line per instr.
__device__ inline void store_row_swz(uint4* dst4, int i, const unsigned short* s) {
    unsigned int w[16];
#pragma unroll
    for (int k = 0; k < 16; ++k)
        w[k] = (unsigned int)s[2*k] | ((unsigned int)s[2*k+1] << 16);
    const int base = (i >> 4) * 64 + (i & 15);
#pragma unroll
    for (int kgc = 0; kgc < 4; ++kgc)
        dst4[base + kgc * 16] = make_uint4(w[4*kgc], w[4*kgc+1],
                                           w[4*kgc+2], w[4*kgc+3]);
}

__global__ __launch_bounds__(256) void pack_points(
        const float* __restrict__ pred, const float* __restrict__ gt,
        unsigned short* __restrict__ Ppa, unsigned short* __restrict__ Ppb,
        unsigned short* __restrict__ Pga, unsigned short* __restrict__ Pgb,
        float* __restrict__ out) {
    const int i = blockIdx.x * 256 + threadIdx.x;
    if (i == 0) out[0] = 0.0f;  // replaces a memset dispatch
    if (i >= NPTS) return;
    float p[3] = {pred[3*i], pred[3*i+1], pred[3*i+2]};
    float q[3] = {gt[3*i],   gt[3*i+1],   gt[3*i+2]};
    unsigned short ra[32], rb[32];
    build_rows(p, ra, rb);
    store_row_swz(reinterpret_cast<uint4*>(Ppa), i, ra);
    store_row_swz(reinterpret_cast<uint4*>(Ppb), i, rb);
    build_rows(q, ra, rb);
    store_row_swz(reinterpret_cast<uint4*>(Pga), i, ra);
    store_row_swz(reinterpret_cast<uint4*>(Pgb), i, rb);
}

// DPP rotate-max within 16-lane rows (VALU pipe; verified R6-R15).
template <int CTRL>
__device__ inline float rormax(float v) {
    int t = __builtin_amdgcn_update_dpp(0, __float_as_int(v), CTRL, 0xF, 0xF,
                                        false);
    return fmaxf(v, __int_as_float(t));
}

__global__ __launch_bounds__(BLOCK, 1) void chamfer_rowmin(
        const unsigned short* __restrict__ Ppa,
        const unsigned short* __restrict__ Ppb,
        const unsigned short* __restrict__ Pga,
        const unsigned short* __restrict__ Pgb,
        float* __restrict__ part) {
    const int xb  = blockIdx.x;
    const int yr  = blockIdx.y;
    const int dir = blockIdx.z;
    const unsigned short* __restrict__ Ap = dir ? Pga : Ppa;  // rows = X side
    const unsigned short* __restrict__ Bp = dir ? Ppb : Pgb;  // cols = Y side
    const int tid = threadIdx.x;
    const int lane = tid & 63, w = tid >> 6;
    const int col = lane & 15, kg = lane >> 4;
    const int frag = kg * 16 + col;      // uint4 index of this lane's frag

    __shared__ uint4 buf[2][CHT * 64];   // 2 x 8 KB B double-buffer
    __shared__ float rowacc[XCH];        // 2 KB epilogue buffer

    // A-frags: wave's 8 x-tiles (each load = contiguous 1KB line)
    const uint4* ap = reinterpret_cast<const uint4*>(Ap);
    const int tile0 = xb * 32 + w * 8;
    u32x4 af[8];
#pragma unroll
    for (int xi = 0; xi < 8; ++xi)
        af[xi] = *reinterpret_cast<const u32x4*>(&ap[(tile0 + xi) * 64 + frag]);

    f32x4 rmax[8];
#pragma unroll
    for (int xi = 0; xi < 8; ++xi)
        rmax[xi] = (f32x4){-3.0e38f, -3.0e38f, -3.0e38f, -3.0e38f};

    const u32x4 zz = {0u, 0u, 0u, 0u};

    // B chunks: block's 4 waves SHARE each 8KB chunk via LDS.
    const uint4* bp = reinterpret_cast<const uint4*>(Bp) + (size_t)(yr * 64) * 64;
    uint4 s0 = bp[tid];                  // prologue: chunk 0 into regs
    uint4 s1 = bp[256 + tid];

#pragma unroll 1
    for (int c = 0; c < NCH; ++c) {
        // write staged chunk; single barrier per chunk (double buffer:
        // buf[c&1] was last read at iter c-2, all waves past bar(c-1))
        buf[c & 1][tid]       = s0;
        buf[c & 1][256 + tid] = s1;
        __syncthreads();
        if (c + 1 < NCH) {               // issue next chunk's loads now;
            s0 = bp[(c + 1) * 512 + tid];        // L2 latency hides under
            s1 = bp[(c + 1) * 512 + 256 + tid];  // this chunk's 64 MFMAs
        }
        const uint4* bb = buf[c & 1];
#pragma unroll
        for (int t = 0; t < CHT; t += 2) {
            u32x4 c0 = *reinterpret_cast<const u32x4*>(&bb[(t + 0) * 64 + frag]);
            u32x4 c1 = *reinterpret_cast<const u32x4*>(&bb[(t + 1) * 64 + frag]);
#pragma unroll
            for (int xi = 0; xi < 8; ++xi) {
                f32x4 A, B;
                // R15-verified: arch-VGPR-forced MFMA + hazard padding
                asm("s_nop 1\n\t"
                    "v_mfma_f32_16x16x32_bf16 %0, %2, %3, %5\n\t"
                    "v_mfma_f32_16x16x32_bf16 %1, %2, %4, %5\n\t"
                    "s_nop 7\n\t"
                    "s_nop 7\n\t"
                    "s_nop 3"
                    : "=&v"(A), "=&v"(B)
                    : "v"(af[xi]), "v"(c0), "v"(c1), "v"(zz));
                rmax[xi].x = fmaxf(fmaxf(A.x, B.x), rmax[xi].x);  // v_max3
                rmax[xi].y = fmaxf(fmaxf(A.y, B.y), rmax[xi].y);
                rmax[xi].z = fmaxf(fmaxf(A.z, B.z), rmax[xi].z);
                rmax[xi].w = fmaxf(fmaxf(A.w, B.w), rmax[xi].w);
            }
        }
        __syncthreads();  // all reads of buf[c&1] done before c+2 overwrite
    }

    // flush ONCE per wave: DPP ror-max over 16 cols, park in LDS,
    // one coalesced 2KB store per block.
#pragma unroll
    for (int xi = 0; xi < 8; ++xi) {
#pragma unroll
        for (int cc = 0; cc < 4; ++cc) {
            float v = rmax[xi][cc];
            v = rormax<0x121>(v);
            v = rormax<0x122>(v);
            v = rormax<0x124>(v);
            v = rormax<0x128>(v);
            if (col == 0)
                rowacc[w * XW + xi * 16 + kg * 4 + cc] = fmaxf(-2.0f * v, 0.0f);
        }
    }
    __syncthreads();
    float* dst = part + (size_t)(dir * NYR + yr) * NPTS + xb * XCH;
    dst[tid]       = rowacc[tid];
    dst[256 + tid] = rowacc[256 + tid];
}

__global__ __launch_bounds__(256) void chamfer_reduce(
        const float* __restrict__ part, float* __restrict__ out) {
    const int gid = blockIdx.x * 256 + threadIdx.x;  // 32 blocks x 256
    const int side = gid >> 12;                      // 4096 f32x4 per side
    const int idx4 = (gid & 4095) * 4;
    const float* base = part + (size_t)side * NYR * NPTS + idx4;
    float4 m = make_float4(3.0e38f, 3.0e38f, 3.0e38f, 3.0e38f);
#pragma unroll
    for (int c = 0; c < NYR; ++c) {
        float4 v = *reinterpret_cast<const float4*>(base + (size_t)c * NPTS);
        m.x = fminf(m.x, v.x); m.y = fminf(m.y, v.y);
        m.z = fminf(m.z, v.z); m.w = fminf(m.w, v.w);
    }
    float s = sqrtf(m.x) + sqrtf(m.y) + sqrtf(m.z) + sqrtf(m.w);
#pragma unroll
    for (int o = 32; o > 0; o >>= 1)
        s += __shfl_down(s, o, 64);
    if ((threadIdx.x & 63) == 0)
        atomicAdd(out, s * (1.0f / (float)NPTS));
}

extern "C" void kernel_launch(void* const* d_in, const int* in_sizes, int n_in,
                              void* d_out, int out_size, void* d_ws, size_t ws_size,
                              hipStream_t stream) {
    const float* pred = (const float*)d_in[0];
    const float* gt   = (const float*)d_in[1];
    float* out        = (float*)d_out;
    unsigned short* Ppa = (unsigned short*)d_ws;
    unsigned short* Ppb = (unsigned short*)((char*)d_ws + WS_PPB);
    unsigned short* Pga = (unsigned short*)((char*)d_ws + WS_PGA);
    unsigned short* Pgb = (unsigned short*)((char*)d_ws + WS_PGB);
    float* part         = (float*)((char*)d_ws + WS_PART);

    hipLaunchKernelGGL(pack_points, dim3(NPTS / 256), dim3(256), 0, stream,
                       pred, gt, Ppa, Ppb, Pga, Pgb, out);
    hipLaunchKernelGGL(chamfer_rowmin, dim3(NXB, NYR, 2), dim3(BLOCK), 0, stream,
                       Ppa, Ppb, Pga, Pgb, part);
    hipLaunchKernelGGL(chamfer_reduce, dim3(2 * NPTS / 1024), dim3(256), 0, stream,
                       part, out);
}